// Round 21
// baseline (1676.893 us; speedup 1.0000x reference)
//
#include <hip/hip_runtime.h>
#include <hip/hip_bf16.h>

// B=1024, L=100, D=512, 2 layers. Outputs: x'[B,L,D] f32 then seq_emb[B,D] f32.
#define B_ 1024
#define L_ 100
#define D_ 512
#define LP 128                    // padded L for MFMA tiles
#define ROWS (B_*L_)              // 102400
#define XELEMS ((size_t)ROWS*D_)  // 52428800
#define HB 512                    // batches per half
#define HR (HB*L_)                // rows per half = 51200
#define CATW 1536                 // cat row stride: [msg(512) | xbf16(512) | xr(512)]

typedef __attribute__((ext_vector_type(8))) short short8;
typedef __attribute__((ext_vector_type(4))) float f32x4;
typedef unsigned long long ull_t;

__device__ __forceinline__ short f2bf(float f) {
    __hip_bfloat16 h = __float2bfloat16(f);
    return *reinterpret_cast<short*>(&h);
}
__device__ __forceinline__ float bf2f(short s) {
    __hip_bfloat16 h = *reinterpret_cast<__hip_bfloat16*>(&s);
    return __bfloat162float(h);
}

__device__ __forceinline__ void cp16(void* lds, const void* g) {
    __builtin_amdgcn_global_load_lds(
        (const __attribute__((address_space(1))) unsigned int*)g,
        (__attribute__((address_space(3))) unsigned int*)lds, 16, 0, 0);
}

__device__ __forceinline__ f32x4 mfma16(short8 a, short8 b, f32x4 c) {
    return __builtin_amdgcn_mfma_f32_16x16x32_bf16(a, b, c, 0, 0, 0);
}

// ---------------- positional encoding ----------------
__global__ __launch_bounds__(256) void pe_kernel(float* __restrict__ pe) {
    int idx = blockIdx.x * 256 + threadIdx.x;
    if (idx >= L_ * D_) return;
    int l = idx >> 9;
    int d = idx & 511;
    int i = d >> 1;
    float div = __expf((float)(2 * i) * (-9.210340371976184f / 512.0f));
    float angle = (float)l * div;
    pe[idx] = (d & 1) ? __cosf(angle) : __sinf(angle);
}

// ---------------- weight transpose+cvt: W[k][n] f32 -> Wt[n][k] bf16 ----------------
__global__ __launch_bounds__(256) void cvtw_kernel(const float* __restrict__ W,
                                                   __hip_bfloat16* __restrict__ Wt) {
    int idx = blockIdx.x * 256 + threadIdx.x;   // over 512*1024
    int n = idx >> 10, k = idx & 1023;
    Wt[idx] = __float2bfloat16(W[(size_t)k * D_ + n]);
}

// ------- fused attention, SPLIT-Q: 2 blocks per batch (64 query rows each) -------
// grid = HB*2; bl = blockIdx.x>>1 (batch), qb = blockIdx.x&1 (query sub-block).
// Phase 0 (x transpose + cat-x) duplicated by both blocks (identical writes, benign;
// each block reads only its own output, drained by its own barriers).
// Phase A stages full XP tile (B operand needs all 128 rows) but computes only
// rows [qb*64, qb*64+64). P = [64][256B]. LDS 32KB -> 4 blocks/CU at grid 1024.
template<int BF16IN>
__global__ __launch_bounds__(256) void attn_kernel(
    const float* __restrict__ x, const float* __restrict__ pe,
    const int* __restrict__ text_len, __hip_bfloat16* __restrict__ xTb,
    __hip_bfloat16* __restrict__ cat, int bh)
{
    __shared__ __align__(16) char sm[16384 + 16384];
    char* XP = sm;             // phase0: t-buf; phaseA: [128][64] swizzled; phaseC: TW
    char* P  = sm + 16384;     // [64][128] bf16, swizzled, rowbytes=256
    const int bl = blockIdx.x >> 1;
    const int qb = blockIdx.x & 1;
    const int b = bh * HB + bl;
    const int len = text_len[b];
    const int tid = threadIdx.x;
    const int w = tid >> 6, g = (tid >> 4) & 3, cl = tid & 15;
    const int lane = tid & 63;
    const float* xb = x + (size_t)b * L_ * D_;   // only valid when BF16IN==0
    __hip_bfloat16* xTg = xTb + (size_t)bl * D_ * LP;

    // ---- phase 0: per-batch transpose x -> xT (+ cat-x write when f32 source) ----
    {
        __hip_bfloat16 (*t)[66] = (__hip_bfloat16 (*)[66])XP;
        for (int d0 = 0; d0 < D_; d0 += 64) {
            for (int l0 = 0; l0 < LP; l0 += 64) {
                int l_loc = tid >> 2;
                int dq = tid & 3;
                int l = l0 + l_loc;
                #pragma unroll
                for (int i = 0; i < 4; ++i) {
                    int d_loc = (dq * 4 + i) * 4;
                    if constexpr (BF16IN) {
                        ull_t u = 0ull;
                        if (l < L_)
                            u = *(const ull_t*)(cat + ((size_t)bl * L_ + l) * CATW + 512 + d0 + d_loc);
                        union { ull_t u; short s[4]; } pk;
                        pk.u = u;
                        t[l_loc][d_loc + 0] = *reinterpret_cast<__hip_bfloat16*>(&pk.s[0]);
                        t[l_loc][d_loc + 1] = *reinterpret_cast<__hip_bfloat16*>(&pk.s[1]);
                        t[l_loc][d_loc + 2] = *reinterpret_cast<__hip_bfloat16*>(&pk.s[2]);
                        t[l_loc][d_loc + 3] = *reinterpret_cast<__hip_bfloat16*>(&pk.s[3]);
                    } else {
                        float4 v = (l < L_) ? *(const float4*)(xb + (size_t)l * D_ + d0 + d_loc)
                                            : make_float4(0.f, 0.f, 0.f, 0.f);
                        short s0 = f2bf(v.x), s1 = f2bf(v.y), s2 = f2bf(v.z), s3 = f2bf(v.w);
                        t[l_loc][d_loc + 0] = *reinterpret_cast<__hip_bfloat16*>(&s0);
                        t[l_loc][d_loc + 1] = *reinterpret_cast<__hip_bfloat16*>(&s1);
                        t[l_loc][d_loc + 2] = *reinterpret_cast<__hip_bfloat16*>(&s2);
                        t[l_loc][d_loc + 3] = *reinterpret_cast<__hip_bfloat16*>(&s3);
                        if (l < L_) {
                            union { short s[4]; ull_t u; } pk;
                            pk.s[0] = s0; pk.s[1] = s1; pk.s[2] = s2; pk.s[3] = s3;
                            *(ull_t*)(cat + ((size_t)bl * L_ + l) * CATW + 512 + d0 + d_loc) = pk.u;
                        }
                    }
                }
                __syncthreads();
                int dl = tid >> 2, seg = tid & 3;
                short8 lo, hi;
                #pragma unroll
                for (int j = 0; j < 8; ++j) {
                    __hip_bfloat16 a = t[seg * 16 + j][dl];
                    __hip_bfloat16 bswap = t[seg * 16 + 8 + j][dl];
                    lo[j] = *reinterpret_cast<short*>(&a);
                    hi[j] = *reinterpret_cast<short*>(&bswap);
                }
                __hip_bfloat16* dst = xTg + (size_t)(d0 + dl) * LP + l0 + seg * 16;
                *(short8*)dst = lo;
                *(short8*)(dst + 8) = hi;
                __syncthreads();
            }
        }
    }

    f32x4 accS[8];
    const f32x4 fz = {0.f, 0.f, 0.f, 0.f};
    #pragma unroll
    for (int j = 0; j < 8; ++j) accS[j] = fz;

    // ---- phase A: S[qb rows] = xp @ xp^T  (x from cat bf16; full XP staged) ----
    for (int kc = 0; kc < D_; kc += 64) {
        #pragma unroll
        for (int i = 0; i < 4; ++i) {
            int c = tid + 256 * i;
            int row = c >> 3, k8d = c & 7;
            int k = kc + 8 * (k8d ^ (row & 7));
            if (row < L_) {
                const float* pp = pe + row * D_ + k;
                float4 b0 = *(const float4*)pp, b1 = *(const float4*)(pp + 4);
                short8 xv = *(const short8*)(cat + ((size_t)bl * L_ + row) * CATW + 512 + k);
                short8 h;
                h[0] = f2bf(bf2f(xv[0]) + b0.x); h[1] = f2bf(bf2f(xv[1]) + b0.y);
                h[2] = f2bf(bf2f(xv[2]) + b0.z); h[3] = f2bf(bf2f(xv[3]) + b0.w);
                h[4] = f2bf(bf2f(xv[4]) + b1.x); h[5] = f2bf(bf2f(xv[5]) + b1.y);
                h[6] = f2bf(bf2f(xv[6]) + b1.z); h[7] = f2bf(bf2f(xv[7]) + b1.w);
                *(short8*)(XP + row * 128 + 16 * k8d) = h;
            } else if (kc == 0) {
                short8 h;
                #pragma unroll
                for (int q = 0; q < 8; ++q) h[q] = 0;
                *(short8*)(XP + row * 128 + 16 * k8d) = h;   // stays 0 for all kc
            }
        }
        __syncthreads();
        #pragma unroll
        for (int kt = 0; kt < 2; ++kt) {
            int r = qb * 64 + 16 * w + cl;
            short8 a = *(const short8*)(XP + r * 128 + ((16 * g + 64 * kt) ^ ((r & 7) << 4)));
            #pragma unroll
            for (int ct = 0; ct < 8; ++ct) {
                int m = 16 * ct + cl;
                short8 bb = *(const short8*)(XP + m * 128 + ((16 * g + 64 * kt) ^ ((m & 7) << 4)));
                accS[ct] = mfma16(a, bb, accS[ct]);
            }
        }
        __syncthreads();
    }

    // ---- phase B: masked softmax (reference MASK_FILL=1e-10, pads excluded) ----
    #pragma unroll
    for (int reg = 0; reg < 4; ++reg) {
        int rlq = 16 * w + 4 * g + reg;        // local 0..63
        int rl = qb * 64 + rlq;                // global S row
        float s[8];
        #pragma unroll
        for (int ct = 0; ct < 8; ++ct) {
            int col = 16 * ct + cl;
            float v = accS[ct][reg];
            if (col >= L_) v = -INFINITY;                  // padding: excluded
            else if (rl >= len || col >= len) v = 1e-10f;  // MASK_FILL
            s[ct] = v;
        }
        float mx = s[0];
        #pragma unroll
        for (int ct = 1; ct < 8; ++ct) mx = fmaxf(mx, s[ct]);
        mx = fmaxf(mx, __shfl_xor(mx, 1));
        mx = fmaxf(mx, __shfl_xor(mx, 2));
        mx = fmaxf(mx, __shfl_xor(mx, 4));
        mx = fmaxf(mx, __shfl_xor(mx, 8));
        float e[8], sum = 0.f;
        #pragma unroll
        for (int ct = 0; ct < 8; ++ct) { e[ct] = __expf(s[ct] - mx); sum += e[ct]; }
        sum += __shfl_xor(sum, 1);
        sum += __shfl_xor(sum, 2);
        sum += __shfl_xor(sum, 4);
        sum += __shfl_xor(sum, 8);
        float inv = 1.f / sum;
        #pragma unroll
        for (int ct = 0; ct < 8; ++ct) {
            int col = 16 * ct + cl;
            *(short*)(P + rlq * 256 + ((col * 2) ^ ((rlq & 7) << 4))) = f2bf(e[ct] * inv);
        }
    }
    // P rows [16w,16w+16) are written and read only by wave w: no barrier needed.

    // ---- phase C: message = P @ x -> cat[:,0:512], per-wave LDS-transposed stores ----
    const __hip_bfloat16* xT = xTg;
    char* TW = XP + w * 4096;   // [16 rows][256B], XOR-swizzled, wave-private
    for (int nc = 0; nc < 4; ++nc) {
        f32x4 accM[8];
        #pragma unroll
        for (int j = 0; j < 8; ++j) accM[j] = fz;
        #pragma unroll
        for (int kt = 0; kt < 4; ++kt) {
            int r = 16 * w + cl;
            short8 a = *(const short8*)(P + r * 256 + ((16 * g + 64 * kt) ^ ((r & 7) << 4)));
            #pragma unroll
            for (int nt = 0; nt < 8; ++nt) {
                int d = nc * 128 + nt * 16 + cl;
                short8 bb = *(const short8*)(xT + (size_t)d * LP + 8 * g + 32 * kt);
                accM[nt] = mfma16(a, bb, accM[nt]);
            }
        }
        #pragma unroll
        for (int nt = 0; nt < 8; ++nt) {
            #pragma unroll
            for (int reg = 0; reg < 4; ++reg) {
                int rloc = 4 * g + reg;              // 0..15
                int cc = nt * 16 + cl;               // 0..127
                *(short*)(TW + rloc * 256 + ((2 * cc) ^ ((rloc & 15) << 4))) =
                    f2bf(accM[nt][reg]);
            }
        }
        asm volatile("s_waitcnt lgkmcnt(0)" ::: "memory");
        __builtin_amdgcn_sched_barrier(0);
        // row-contiguous read-back: 16 lanes per row (256B contiguous), 4 rows/instr
        {
            int r4 = lane >> 4;            // 0..3
            int c16 = lane & 15;           // 16B chunk
            #pragma unroll
            for (int it = 0; it < 4; ++it) {
                int rloc = it * 4 + r4;    // 0..15
                int rl = qb * 64 + 16 * w + rloc;
                if (rl < L_) {
                    int byte = (c16 * 16) ^ ((rloc & 15) << 4);
                    short8 v = *(const short8*)(TW + rloc * 256 + byte);
                    int d = nc * 128 + c16 * 8;
                    *(short8*)(cat + ((size_t)bl * L_ + rl) * CATW + d) = v;
                }
            }
        }
        asm volatile("s_waitcnt lgkmcnt(0)" ::: "memory");
        __builtin_amdgcn_sched_barrier(0);
    }
}

// --- 128x128 BK=32 4-wave TRIPLE-buffered GEMM: depth-2 prefetch, one barrier/iter ---
// R18-verified config (0 conflicts, ideal WRITE_SIZE). Grids must be % 8 == 0.
// MODE 0: N=1024, B=Wur^T, A = cat[:,0:1024]; sigmoid -> upd / cat-xr. Grid 3200.
// MODE 1: N=512,  B=Wo^T,  A = cat cols {0:512, 1024:1536}; GRU combine. Grid 1600.
template<int MODE, int LAST>
__global__ __launch_bounds__(256) void gemm_gates(
    const __hip_bfloat16* __restrict__ cat,
    const __hip_bfloat16* __restrict__ Wt,
    const float* __restrict__ bias0, const float* __restrict__ bias1,
    __hip_bfloat16* __restrict__ upd,       // MODE0: write; MODE1: read
    __hip_bfloat16* __restrict__ catw,      // writable cat alias
    float* __restrict__ xdst)               // MODE1+LAST: f32 x output (half-local)
{
    __shared__ __align__(16) char sm[49152];   // 3 x 16KB rotation; T reuses bufs 0-1
    const int tid = threadIdx.x;
    const int w = tid >> 6, g = (tid >> 4) & 3, cl = tid & 15;
    const int wr = w >> 1, wc = w & 1;
    constexpr int NY = (MODE == 0) ? 8 : 4;
    const int cpx = gridDim.x >> 3;
    const int bid = blockIdx.x;
    const int swz = (bid & 7) * cpx + (bid >> 3);   // bijective: grid % 8 == 0
    const int bx = swz / NY, by = swz % NY;         // row-major logical: A-locality per XCD
    const size_t R0 = (size_t)bx * 128;
    const int col0 = by * 128;

    // per-thread staging geometry: chunk p -> (tile row, k-slot byte offset)
    int srow[2], skoff[2];
    #pragma unroll
    for (int i = 0; i < 2; ++i) {
        int p = tid + 256 * i;
        int R = p >> 3, s = p & 7;
        int u = s ^ (R & 7);
        srow[i] = 2 * R + (u >> 2);
        skoff[i] = (u & 3) * 16;                 // bytes within the row's 64B
    }

    auto stage = [&](int t, char* buf) {
        const int kc = t * 32;                                      // B k-offset (elems)
        const int ka = (MODE == 0) ? kc : (t < 16 ? kc : kc + 512); // A k-offset (elems)
        #pragma unroll
        for (int i = 0; i < 2; ++i) {
            int p = tid + 256 * i;
            const char* gA = (const char*)(cat + (R0 + srow[i]) * CATW + ka) + skoff[i];
            cp16(buf + p * 16, gA);
        }
        #pragma unroll
        for (int i = 0; i < 2; ++i) {
            int p = tid + 256 * i;
            const char* gB = (const char*)(Wt + (size_t)(col0 + srow[i]) * 1024 + kc) + skoff[i];
            cp16(buf + 8192 + p * 16, gB);
        }
    };

    f32x4 acc[4][4];
    const f32x4 fz = {0.f, 0.f, 0.f, 0.f};
    #pragma unroll
    for (int i = 0; i < 4; ++i)
        #pragma unroll
        for (int j = 0; j < 4; ++j) acc[i][j] = fz;

    stage(0, sm);                       // prologue: tiles 0,1 into buffers 0,1
    stage(1, sm + 16384);
    #pragma unroll 1
    for (int t = 0; t < 32; ++t) {
        char* buf = sm + 16384 * (t % 3);
        if (t < 31) asm volatile("s_waitcnt vmcnt(4)" ::: "memory");  // tile t landed
        else        asm volatile("s_waitcnt vmcnt(0)" ::: "memory");
        __builtin_amdgcn_sched_barrier(0);
        __builtin_amdgcn_s_barrier();   // all waves: tile t visible; iter t-1 reads done
        if (t + 2 < 32)
            stage(t + 2, sm + 16384 * ((t + 2) % 3));   // into (t-1)%3: WAR-safe

        short8 aA[4], bb[4];
        #pragma unroll
        for (int rt = 0; rt < 4; ++rt) {
            int r = wr * 64 + rt * 16 + cl;
            int Rr = r >> 1;
            int sA = (((r & 1) << 2) + g) ^ (Rr & 7);
            aA[rt] = *(const short8*)(buf + Rr * 128 + 16 * sA);
        }
        #pragma unroll
        for (int ct = 0; ct < 4; ++ct) {
            int n = wc * 64 + ct * 16 + cl;
            int Rn = n >> 1;
            int sB = (((n & 1) << 2) + g) ^ (Rn & 7);
            bb[ct] = *(const short8*)(buf + 8192 + Rn * 128 + 16 * sB);
        }
        __builtin_amdgcn_s_setprio(1);
        #pragma unroll
        for (int rt = 0; rt < 4; ++rt)
            #pragma unroll
            for (int ct = 0; ct < 4; ++ct)
                acc[rt][ct] = mfma16(aA[rt], bb[ct], acc[rt][ct]);
        __builtin_amdgcn_s_setprio(0);
    }

    // ---- epilogue: activation -> LDS transpose -> row-contiguous coalesced IO ----
    char* T = sm;   // [128 rows][256B], reuses buffers 0+1
    #pragma unroll
    for (int ct = 0; ct < 4; ++ct) {
        int c = wc * 64 + ct * 16 + cl;        // local col 0..127
        int colg = col0 + c;
        float bb = (MODE == 0) ? ((col0 < 512) ? bias0[colg] : bias1[colg - 512])
                               : bias0[colg];
        #pragma unroll
        for (int rt = 0; rt < 4; ++rt) {
            #pragma unroll
            for (int reg = 0; reg < 4; ++reg) {
                int r = wr * 64 + rt * 16 + g * 4 + reg;
                float z = acc[rt][ct][reg] + bb;
                float v;
                if (MODE == 0) v = 1.f / (1.f + __expf(-z));                        // sigmoid
                else           v = 1.f - 2.f * __fdividef(1.f, 1.f + __expf(2.f * z)); // tanh
                *(short*)(T + r * 256 + ((2 * c) ^ ((r & 15) << 4))) = f2bf(v);
            }
        }
    }
    __syncthreads();
    {
        const int rr = tid >> 4;          // 0..15
        const int c16 = tid & 15;         // 16B chunk -> cols c16*8..+7
        #pragma unroll
        for (int it = 0; it < 8; ++it) {
            int r = it * 16 + rr;
            const size_t grow = R0 + r;
            int byte = (c16 * 16) ^ ((r & 15) << 4);
            short8 v = *(const short8*)(T + r * 256 + byte);
            int colg = col0 + c16 * 8;
            if (MODE == 0) {
                if (col0 < 512) {
                    *(short8*)(upd + grow * D_ + colg) = v;
                } else {
                    int c2 = colg - 512;
                    short8 xv = *(const short8*)(cat + grow * CATW + 512 + c2);
                    short8 o;
                    #pragma unroll
                    for (int q = 0; q < 8; ++q)
                        o[q] = f2bf(bf2f(xv[q]) * bf2f(v[q]));
                    *(short8*)(catw + grow * CATW + 1024 + c2) = o;
                }
            } else {
                short8 uv = *(const short8*)(upd + grow * D_ + colg);
                short8 xv = *(const short8*)(cat + grow * CATW + 512 + colg);
                if (LAST) {
                    float o[8];
                    #pragma unroll
                    for (int q = 0; q < 8; ++q) {
                        float u = bf2f(uv[q]), x_ = bf2f(xv[q]), cd = bf2f(v[q]);
                        o[q] = x_ + u * (cd - x_);
                    }
                    *(float4*)(xdst + grow * D_ + colg)     = make_float4(o[0], o[1], o[2], o[3]);
                    *(float4*)(xdst + grow * D_ + colg + 4) = make_float4(o[4], o[5], o[6], o[7]);
                } else {
                    short8 o;
                    #pragma unroll
                    for (int q = 0; q < 8; ++q) {
                        float u = bf2f(uv[q]), x_ = bf2f(xv[q]), cd = bf2f(v[q]);
                        o[q] = f2bf(x_ + u * (cd - x_));
                    }
                    *(short8*)(catw + grow * CATW + 512 + colg) = o;
                }
            }
        }
    }
}

// ---------------- masked mean pooling ----------------
__global__ __launch_bounds__(256) void pool_kernel(
    const float* __restrict__ x, const int* __restrict__ text_len,
    float* __restrict__ seq)
{
    int b = blockIdx.x;
    int len = text_len[b];
    float invlen = 1.f / (float)len;
    const float* xb = x + (size_t)b * L_ * D_;
    for (int d = threadIdx.x; d < D_; d += 256) {
        float acc = 0.f;
        for (int l = 0; l < len; ++l)
            acc += xb[(size_t)l * D_ + d];
        seq[(size_t)b * D_ + d] = acc * invlen;
    }
}

extern "C" void kernel_launch(void* const* d_in, const int* in_sizes, int n_in,
                              void* d_out, int out_size, void* d_ws, size_t ws_size,
                              hipStream_t stream) {
    const float* x_in = (const float*)d_in[0];
    const int* text_len = (const int*)d_in[1];
    const float* W_r = (const float*)d_in[2];
    const float* b_r = (const float*)d_in[3];
    const float* W_u = (const float*)d_in[4];
    const float* b_u = (const float*)d_in[5];
    const float* W_o = (const float*)d_in[6];
    const float* b_o = (const float*)d_in[7];

    float* xwork = (float*)d_out;
    float* seq_out = (float*)d_out + XELEMS;

    char* ws = (char*)d_ws;
    float* pe            = (float*)ws;                         // 204800 B
    __hip_bfloat16* WurT = (__hip_bfloat16*)(ws + 204800);     // [1024][1024] bf16 (u rows 0-511, r rows 512-1023)
    __hip_bfloat16* WoT  = (__hip_bfloat16*)(ws + 2301952);    // [512][1024] bf16
    __hip_bfloat16* cat  = (__hip_bfloat16*)(ws + 3350528);    // [51200][1536] bf16 (per-half; L3-resident)
    char* unionR         = ws + 160636928ull;                  // 67108864 B
    __hip_bfloat16* xTb  = (__hip_bfloat16*)unionR;            // [512][512][128] bf16
    __hip_bfloat16* upd  = (__hip_bfloat16*)unionR;            // [51200][512] bf16 (aliased; disjoint lifetime)

    pe_kernel<<<(L_ * D_ + 255) / 256, 256, 0, stream>>>(pe);
    cvtw_kernel<<<2048, 256, 0, stream>>>(W_u, WurT);
    cvtw_kernel<<<2048, 256, 0, stream>>>(W_r, WurT + 512 * 1024);
    cvtw_kernel<<<2048, 256, 0, stream>>>(W_o, WoT);

    // half-outer order: cat persists per-half across both layers; x-chain bf16 in cat.
    // Half-batch keeps cat (157MB) L3-resident — full-batch cat (315MB) thrashes L3 (R19).
    for (int h = 0; h < 2; ++h) {
        float* xdh = xwork + (size_t)h * HR * D_;
        // ---- layer 0: x from x_in f32 (phase 0 converts + transposes) ----
        attn_kernel<0><<<HB * 2, 256, 0, stream>>>(x_in, pe, text_len, xTb, cat, h);
        gemm_gates<0, 0><<<3200, 256, 0, stream>>>(cat, WurT, b_u, b_r, upd, cat, nullptr);
        gemm_gates<1, 0><<<1600, 256, 0, stream>>>(cat, WoT, b_o, nullptr, upd, cat, nullptr);
        // ---- layer 1: x from cat bf16 (written in-place by layer-0 MODE1) ----
        attn_kernel<1><<<HB * 2, 256, 0, stream>>>(nullptr, pe, text_len, xTb, cat, h);
        gemm_gates<0, 0><<<3200, 256, 0, stream>>>(cat, WurT, b_u, b_r, upd, cat, nullptr);
        gemm_gates<1, 1><<<1600, 256, 0, stream>>>(cat, WoT, b_o, nullptr, upd, cat, xdh);
    }
    pool_kernel<<<B_, 256, 0, stream>>>(xwork, text_len, seq_out);
}

// Round 22
// 1452.913 us; speedup vs baseline: 1.1542x; 1.1542x over previous
//
#include <hip/hip_runtime.h>
#include <hip/hip_bf16.h>

// B=1024, L=100, D=512, 2 layers. Outputs: x'[B,L,D] f32 then seq_emb[B,D] f32.
#define B_ 1024
#define L_ 100
#define D_ 512
#define LP 128                    // padded L for MFMA tiles
#define ROWS (B_*L_)              // 102400
#define XELEMS ((size_t)ROWS*D_)  // 52428800
#define HB 512                    // batches per half
#define HR (HB*L_)                // rows per half = 51200
#define CATW 1536                 // cat row stride: [msg(512) | xbf16(512) | xr(512)]

typedef __attribute__((ext_vector_type(8))) short short8;
typedef __attribute__((ext_vector_type(4))) float f32x4;
typedef unsigned long long ull_t;

__device__ __forceinline__ short f2bf(float f) {
    __hip_bfloat16 h = __float2bfloat16(f);
    return *reinterpret_cast<short*>(&h);
}
__device__ __forceinline__ float bf2f(short s) {
    __hip_bfloat16 h = *reinterpret_cast<__hip_bfloat16*>(&s);
    return __bfloat162float(h);
}

__device__ __forceinline__ void cp16(void* lds, const void* g) {
    __builtin_amdgcn_global_load_lds(
        (const __attribute__((address_space(1))) unsigned int*)g,
        (__attribute__((address_space(3))) unsigned int*)lds, 16, 0, 0);
}

__device__ __forceinline__ f32x4 mfma16(short8 a, short8 b, f32x4 c) {
    return __builtin_amdgcn_mfma_f32_16x16x32_bf16(a, b, c, 0, 0, 0);
}

// ---------------- positional encoding ----------------
__global__ __launch_bounds__(256) void pe_kernel(float* __restrict__ pe) {
    int idx = blockIdx.x * 256 + threadIdx.x;
    if (idx >= L_ * D_) return;
    int l = idx >> 9;
    int d = idx & 511;
    int i = d >> 1;
    float div = __expf((float)(2 * i) * (-9.210340371976184f / 512.0f));
    float angle = (float)l * div;
    pe[idx] = (d & 1) ? __cosf(angle) : __sinf(angle);
}

// ---------------- weight transpose+cvt: W[k][n] f32 -> Wt[n][k] bf16 ----------------
__global__ __launch_bounds__(256) void cvtw_kernel(const float* __restrict__ W,
                                                   __hip_bfloat16* __restrict__ Wt) {
    int idx = blockIdx.x * 256 + threadIdx.x;   // over 512*1024
    int n = idx >> 10, k = idx & 1023;
    Wt[idx] = __float2bfloat16(W[(size_t)k * D_ + n]);
}

// ---------------- fused attention (+ inline x-transpose prep), 4 waves ----------------
template<int BF16IN>
__global__ __launch_bounds__(256) void attn_kernel(
    const float* __restrict__ x, const float* __restrict__ pe,
    const int* __restrict__ text_len, __hip_bfloat16* __restrict__ xTb,
    __hip_bfloat16* __restrict__ cat, int bh)
{
    __shared__ __align__(16) char sm[16384 + 32768];
    char* XP = sm;             // phase0: t-buf; phaseA: [128][64] swizzled; phaseC: T-buf
    char* P  = sm + 16384;     // [128][128] bf16, swizzled, rowbytes=256
    const int bl = blockIdx.x;
    const int b = bh * HB + bl;
    const int len = text_len[b];
    const int tid = threadIdx.x;
    const int w = tid >> 6, g = (tid >> 4) & 3, cl = tid & 15;
    const int lane = tid & 63;
    const float* xb = x + (size_t)b * L_ * D_;   // only valid when BF16IN==0
    __hip_bfloat16* xTg = xTb + (size_t)bl * D_ * LP;

    // ---- phase 0: per-batch transpose x -> xT (+ cat-x write when f32 source) ----
    {
        __hip_bfloat16 (*t)[66] = (__hip_bfloat16 (*)[66])XP;
        for (int d0 = 0; d0 < D_; d0 += 64) {
            for (int l0 = 0; l0 < LP; l0 += 64) {
                int l_loc = tid >> 2;
                int dq = tid & 3;
                int l = l0 + l_loc;
                #pragma unroll
                for (int i = 0; i < 4; ++i) {
                    int d_loc = (dq * 4 + i) * 4;
                    if constexpr (BF16IN) {
                        ull_t u = 0ull;
                        if (l < L_)
                            u = *(const ull_t*)(cat + ((size_t)bl * L_ + l) * CATW + 512 + d0 + d_loc);
                        union { ull_t u; short s[4]; } pk;
                        pk.u = u;
                        t[l_loc][d_loc + 0] = *reinterpret_cast<__hip_bfloat16*>(&pk.s[0]);
                        t[l_loc][d_loc + 1] = *reinterpret_cast<__hip_bfloat16*>(&pk.s[1]);
                        t[l_loc][d_loc + 2] = *reinterpret_cast<__hip_bfloat16*>(&pk.s[2]);
                        t[l_loc][d_loc + 3] = *reinterpret_cast<__hip_bfloat16*>(&pk.s[3]);
                    } else {
                        float4 v = (l < L_) ? *(const float4*)(xb + (size_t)l * D_ + d0 + d_loc)
                                            : make_float4(0.f, 0.f, 0.f, 0.f);
                        short s0 = f2bf(v.x), s1 = f2bf(v.y), s2 = f2bf(v.z), s3 = f2bf(v.w);
                        t[l_loc][d_loc + 0] = *reinterpret_cast<__hip_bfloat16*>(&s0);
                        t[l_loc][d_loc + 1] = *reinterpret_cast<__hip_bfloat16*>(&s1);
                        t[l_loc][d_loc + 2] = *reinterpret_cast<__hip_bfloat16*>(&s2);
                        t[l_loc][d_loc + 3] = *reinterpret_cast<__hip_bfloat16*>(&s3);
                        if (l < L_) {
                            union { short s[4]; ull_t u; } pk;
                            pk.s[0] = s0; pk.s[1] = s1; pk.s[2] = s2; pk.s[3] = s3;
                            *(ull_t*)(cat + ((size_t)bl * L_ + l) * CATW + 512 + d0 + d_loc) = pk.u;
                        }
                    }
                }
                __syncthreads();
                int dl = tid >> 2, seg = tid & 3;
                short8 lo, hi;
                #pragma unroll
                for (int j = 0; j < 8; ++j) {
                    __hip_bfloat16 a = t[seg * 16 + j][dl];
                    __hip_bfloat16 bswap = t[seg * 16 + 8 + j][dl];
                    lo[j] = *reinterpret_cast<short*>(&a);
                    hi[j] = *reinterpret_cast<short*>(&bswap);
                }
                __hip_bfloat16* dst = xTg + (size_t)(d0 + dl) * LP + l0 + seg * 16;
                *(short8*)dst = lo;
                *(short8*)(dst + 8) = hi;
                __syncthreads();
            }
        }
    }

    f32x4 accS[2][8];
    const f32x4 fz = {0.f, 0.f, 0.f, 0.f};
    #pragma unroll
    for (int i = 0; i < 2; ++i)
        #pragma unroll
        for (int j = 0; j < 8; ++j) accS[i][j] = fz;

    // ---- phase A: S = xp @ xp^T  (x from cat bf16) ----
    for (int kc = 0; kc < D_; kc += 64) {
        #pragma unroll
        for (int i = 0; i < 4; ++i) {
            int c = tid + 256 * i;
            int row = c >> 3, k8d = c & 7;
            int k = kc + 8 * (k8d ^ (row & 7));
            if (row < L_) {
                const float* pp = pe + row * D_ + k;
                float4 b0 = *(const float4*)pp, b1 = *(const float4*)(pp + 4);
                short8 xv = *(const short8*)(cat + ((size_t)bl * L_ + row) * CATW + 512 + k);
                short8 h;
                h[0] = f2bf(bf2f(xv[0]) + b0.x); h[1] = f2bf(bf2f(xv[1]) + b0.y);
                h[2] = f2bf(bf2f(xv[2]) + b0.z); h[3] = f2bf(bf2f(xv[3]) + b0.w);
                h[4] = f2bf(bf2f(xv[4]) + b1.x); h[5] = f2bf(bf2f(xv[5]) + b1.y);
                h[6] = f2bf(bf2f(xv[6]) + b1.z); h[7] = f2bf(bf2f(xv[7]) + b1.w);
                *(short8*)(XP + row * 128 + 16 * k8d) = h;
            } else if (kc == 0) {
                short8 h;
                #pragma unroll
                for (int q = 0; q < 8; ++q) h[q] = 0;
                *(short8*)(XP + row * 128 + 16 * k8d) = h;   // stays 0 for all kc
            }
        }
        __syncthreads();
        #pragma unroll
        for (int kt = 0; kt < 2; ++kt) {
            short8 a[2];
            #pragma unroll
            for (int rt = 0; rt < 2; ++rt) {
                int r = 32 * w + 16 * rt + cl;
                a[rt] = *(const short8*)(XP + r * 128 + ((16 * g + 64 * kt) ^ ((r & 7) << 4)));
            }
            #pragma unroll
            for (int ct = 0; ct < 8; ++ct) {
                int m = 16 * ct + cl;
                short8 bb = *(const short8*)(XP + m * 128 + ((16 * g + 64 * kt) ^ ((m & 7) << 4)));
                accS[0][ct] = mfma16(a[0], bb, accS[0][ct]);
                accS[1][ct] = mfma16(a[1], bb, accS[1][ct]);
            }
        }
        __syncthreads();
    }

    // ---- phase B: masked softmax (reference MASK_FILL=1e-10, pads excluded) ----
    #pragma unroll
    for (int rt = 0; rt < 2; ++rt) {
        #pragma unroll
        for (int reg = 0; reg < 4; ++reg) {
            int rl = 32 * w + 16 * rt + 4 * g + reg;
            float s[8];
            #pragma unroll
            for (int ct = 0; ct < 8; ++ct) {
                int col = 16 * ct + cl;
                float v = accS[rt][ct][reg];
                if (col >= L_) v = -INFINITY;                  // padding: excluded
                else if (rl >= len || col >= len) v = 1e-10f;  // MASK_FILL
                s[ct] = v;
            }
            float mx = s[0];
            #pragma unroll
            for (int ct = 1; ct < 8; ++ct) mx = fmaxf(mx, s[ct]);
            mx = fmaxf(mx, __shfl_xor(mx, 1));
            mx = fmaxf(mx, __shfl_xor(mx, 2));
            mx = fmaxf(mx, __shfl_xor(mx, 4));
            mx = fmaxf(mx, __shfl_xor(mx, 8));
            float e[8], sum = 0.f;
            #pragma unroll
            for (int ct = 0; ct < 8; ++ct) { e[ct] = __expf(s[ct] - mx); sum += e[ct]; }
            sum += __shfl_xor(sum, 1);
            sum += __shfl_xor(sum, 2);
            sum += __shfl_xor(sum, 4);
            sum += __shfl_xor(sum, 8);
            float inv = 1.f / sum;
            #pragma unroll
            for (int ct = 0; ct < 8; ++ct) {
                int col = 16 * ct + cl;
                *(short*)(P + rl * 256 + ((col * 2) ^ ((rl & 7) << 4))) = f2bf(e[ct] * inv);
            }
        }
    }
    // P rows [32w,32w+32) are written and read only by wave w: no barrier needed.

    // ---- phase C: message = P @ x -> cat[:,0:512], per-wave LDS-transposed stores ----
    const __hip_bfloat16* xT = xTg;
    char* TW = XP + w * 4096;   // [16 rows][256B], XOR-swizzled, wave-private
    for (int nc = 0; nc < 4; ++nc) {
        f32x4 accM[2][8];
        #pragma unroll
        for (int i = 0; i < 2; ++i)
            #pragma unroll
            for (int j = 0; j < 8; ++j) accM[i][j] = fz;
        #pragma unroll
        for (int kt = 0; kt < 4; ++kt) {
            short8 a[2];
            #pragma unroll
            for (int rt = 0; rt < 2; ++rt) {
                int r = 32 * w + 16 * rt + cl;
                a[rt] = *(const short8*)(P + r * 256 + ((16 * g + 64 * kt) ^ ((r & 7) << 4)));
            }
            #pragma unroll
            for (int nt = 0; nt < 8; ++nt) {
                int d = nc * 128 + nt * 16 + cl;
                short8 bb = *(const short8*)(xT + (size_t)d * LP + 8 * g + 32 * kt);
                accM[0][nt] = mfma16(a[0], bb, accM[0][nt]);
                accM[1][nt] = mfma16(a[1], bb, accM[1][nt]);
            }
        }
        #pragma unroll
        for (int rt = 0; rt < 2; ++rt) {
            #pragma unroll
            for (int nt = 0; nt < 8; ++nt) {
                #pragma unroll
                for (int reg = 0; reg < 4; ++reg) {
                    int rloc = 4 * g + reg;              // 0..15
                    int cc = nt * 16 + cl;               // 0..127
                    *(short*)(TW + rloc * 256 + ((2 * cc) ^ ((rloc & 15) << 4))) =
                        f2bf(accM[rt][nt][reg]);
                }
            }
            asm volatile("s_waitcnt lgkmcnt(0)" ::: "memory");
            __builtin_amdgcn_sched_barrier(0);
            // row-contiguous read-back: 16 lanes per row (256B contiguous), 4 rows/instr
            {
                int r4 = lane >> 4;            // 0..3
                int c16 = lane & 15;           // 16B chunk
                #pragma unroll
                for (int it = 0; it < 4; ++it) {
                    int rloc = it * 4 + r4;    // 0..15
                    int rl = 32 * w + 16 * rt + rloc;
                    if (rl < L_) {
                        int byte = (c16 * 16) ^ ((rloc & 15) << 4);
                        short8 v = *(const short8*)(TW + rloc * 256 + byte);
                        int d = nc * 128 + c16 * 8;
                        *(short8*)(cat + ((size_t)bl * L_ + rl) * CATW + d) = v;
                    }
                }
            }
            asm volatile("s_waitcnt lgkmcnt(0)" ::: "memory");
            __builtin_amdgcn_sched_barrier(0);
        }
    }
}

// --- 128x128 BK=32 4-wave TRIPLE-buffered GEMM: depth-2 prefetch, one barrier/iter ---
// R18-verified config (0 conflicts, ideal WRITE_SIZE). Grids must be % 8 == 0.
// MODE 0: N=1024, B=Wur^T, A = cat[:,0:1024]; sigmoid -> upd / cat-xr. Grid 3200.
// MODE 1: N=512,  B=Wo^T,  A = cat cols {0:512, 1024:1536}; GRU combine. Grid 1600.
template<int MODE, int LAST>
__global__ __launch_bounds__(256) void gemm_gates(
    const __hip_bfloat16* __restrict__ cat,
    const __hip_bfloat16* __restrict__ Wt,
    const float* __restrict__ bias0, const float* __restrict__ bias1,
    __hip_bfloat16* __restrict__ upd,       // MODE0: write; MODE1: read
    __hip_bfloat16* __restrict__ catw,      // writable cat alias
    float* __restrict__ xdst)               // MODE1+LAST: f32 x output (half-local)
{
    __shared__ __align__(16) char sm[49152];   // 3 x 16KB rotation; T reuses bufs 0-1
    const int tid = threadIdx.x;
    const int w = tid >> 6, g = (tid >> 4) & 3, cl = tid & 15;
    const int wr = w >> 1, wc = w & 1;
    constexpr int NY = (MODE == 0) ? 8 : 4;
    const int cpx = gridDim.x >> 3;
    const int bid = blockIdx.x;
    const int swz = (bid & 7) * cpx + (bid >> 3);   // bijective: grid % 8 == 0
    const int bx = swz / NY, by = swz % NY;         // row-major logical: A-locality per XCD
    const size_t R0 = (size_t)bx * 128;
    const int col0 = by * 128;

    // per-thread staging geometry: chunk p -> (tile row, k-slot byte offset)
    int srow[2], skoff[2];
    #pragma unroll
    for (int i = 0; i < 2; ++i) {
        int p = tid + 256 * i;
        int R = p >> 3, s = p & 7;
        int u = s ^ (R & 7);
        srow[i] = 2 * R + (u >> 2);
        skoff[i] = (u & 3) * 16;                 // bytes within the row's 64B
    }

    auto stage = [&](int t, char* buf) {
        const int kc = t * 32;                                      // B k-offset (elems)
        const int ka = (MODE == 0) ? kc : (t < 16 ? kc : kc + 512); // A k-offset (elems)
        #pragma unroll
        for (int i = 0; i < 2; ++i) {
            int p = tid + 256 * i;
            const char* gA = (const char*)(cat + (R0 + srow[i]) * CATW + ka) + skoff[i];
            cp16(buf + p * 16, gA);
        }
        #pragma unroll
        for (int i = 0; i < 2; ++i) {
            int p = tid + 256 * i;
            const char* gB = (const char*)(Wt + (size_t)(col0 + srow[i]) * 1024 + kc) + skoff[i];
            cp16(buf + 8192 + p * 16, gB);
        }
    };

    f32x4 acc[4][4];
    const f32x4 fz = {0.f, 0.f, 0.f, 0.f};
    #pragma unroll
    for (int i = 0; i < 4; ++i)
        #pragma unroll
        for (int j = 0; j < 4; ++j) acc[i][j] = fz;

    stage(0, sm);                       // prologue: tiles 0,1 into buffers 0,1
    stage(1, sm + 16384);
    #pragma unroll 1
    for (int t = 0; t < 32; ++t) {
        char* buf = sm + 16384 * (t % 3);
        if (t < 31) asm volatile("s_waitcnt vmcnt(4)" ::: "memory");  // tile t landed
        else        asm volatile("s_waitcnt vmcnt(0)" ::: "memory");
        __builtin_amdgcn_sched_barrier(0);
        __builtin_amdgcn_s_barrier();   // all waves: tile t visible; iter t-1 reads done
        if (t + 2 < 32)
            stage(t + 2, sm + 16384 * ((t + 2) % 3));   // into (t-1)%3: WAR-safe

        short8 aA[4], bb[4];
        #pragma unroll
        for (int rt = 0; rt < 4; ++rt) {
            int r = wr * 64 + rt * 16 + cl;
            int Rr = r >> 1;
            int sA = (((r & 1) << 2) + g) ^ (Rr & 7);
            aA[rt] = *(const short8*)(buf + Rr * 128 + 16 * sA);
        }
        #pragma unroll
        for (int ct = 0; ct < 4; ++ct) {
            int n = wc * 64 + ct * 16 + cl;
            int Rn = n >> 1;
            int sB = (((n & 1) << 2) + g) ^ (Rn & 7);
            bb[ct] = *(const short8*)(buf + 8192 + Rn * 128 + 16 * sB);
        }
        __builtin_amdgcn_s_setprio(1);
        #pragma unroll
        for (int rt = 0; rt < 4; ++rt)
            #pragma unroll
            for (int ct = 0; ct < 4; ++ct)
                acc[rt][ct] = mfma16(aA[rt], bb[ct], acc[rt][ct]);
        __builtin_amdgcn_s_setprio(0);
    }

    // ---- epilogue: activation -> LDS transpose -> row-contiguous coalesced IO ----
    char* T = sm;   // [128 rows][256B], reuses buffers 0+1
    #pragma unroll
    for (int ct = 0; ct < 4; ++ct) {
        int c = wc * 64 + ct * 16 + cl;        // local col 0..127
        int colg = col0 + c;
        float bb = (MODE == 0) ? ((col0 < 512) ? bias0[colg] : bias1[colg - 512])
                               : bias0[colg];
        #pragma unroll
        for (int rt = 0; rt < 4; ++rt) {
            #pragma unroll
            for (int reg = 0; reg < 4; ++reg) {
                int r = wr * 64 + rt * 16 + g * 4 + reg;
                float z = acc[rt][ct][reg] + bb;
                float v;
                if (MODE == 0) v = 1.f / (1.f + __expf(-z));                        // sigmoid
                else           v = 1.f - 2.f * __fdividef(1.f, 1.f + __expf(2.f * z)); // tanh
                *(short*)(T + r * 256 + ((2 * c) ^ ((r & 15) << 4))) = f2bf(v);
            }
        }
    }
    __syncthreads();
    {
        const int rr = tid >> 4;          // 0..15
        const int c16 = tid & 15;         // 16B chunk -> cols c16*8..+7
        #pragma unroll
        for (int it = 0; it < 8; ++it) {
            int r = it * 16 + rr;
            const size_t grow = R0 + r;
            int byte = (c16 * 16) ^ ((r & 15) << 4);
            short8 v = *(const short8*)(T + r * 256 + byte);
            int colg = col0 + c16 * 8;
            if (MODE == 0) {
                if (col0 < 512) {
                    *(short8*)(upd + grow * D_ + colg) = v;
                } else {
                    int c2 = colg - 512;
                    short8 xv = *(const short8*)(cat + grow * CATW + 512 + c2);
                    short8 o;
                    #pragma unroll
                    for (int q = 0; q < 8; ++q)
                        o[q] = f2bf(bf2f(xv[q]) * bf2f(v[q]));
                    *(short8*)(catw + grow * CATW + 1024 + c2) = o;
                }
            } else {
                short8 uv = *(const short8*)(upd + grow * D_ + colg);
                short8 xv = *(const short8*)(cat + grow * CATW + 512 + colg);
                if (LAST) {
                    float o[8];
                    #pragma unroll
                    for (int q = 0; q < 8; ++q) {
                        float u = bf2f(uv[q]), x_ = bf2f(xv[q]), cd = bf2f(v[q]);
                        o[q] = x_ + u * (cd - x_);
                    }
                    *(float4*)(xdst + grow * D_ + colg)     = make_float4(o[0], o[1], o[2], o[3]);
                    *(float4*)(xdst + grow * D_ + colg + 4) = make_float4(o[4], o[5], o[6], o[7]);
                } else {
                    short8 o;
                    #pragma unroll
                    for (int q = 0; q < 8; ++q) {
                        float u = bf2f(uv[q]), x_ = bf2f(xv[q]), cd = bf2f(v[q]);
                        o[q] = f2bf(x_ + u * (cd - x_));
                    }
                    *(short8*)(catw + grow * CATW + 512 + colg) = o;
                }
            }
        }
    }
}

// ---------------- masked mean pooling ----------------
__global__ __launch_bounds__(256) void pool_kernel(
    const float* __restrict__ x, const int* __restrict__ text_len,
    float* __restrict__ seq)
{
    int b = blockIdx.x;
    int len = text_len[b];
    float invlen = 1.f / (float)len;
    const float* xb = x + (size_t)b * L_ * D_;
    for (int d = threadIdx.x; d < D_; d += 256) {
        float acc = 0.f;
        for (int l = 0; l < len; ++l)
            acc += xb[(size_t)l * D_ + d];
        seq[(size_t)b * D_ + d] = acc * invlen;
    }
}

extern "C" void kernel_launch(void* const* d_in, const int* in_sizes, int n_in,
                              void* d_out, int out_size, void* d_ws, size_t ws_size,
                              hipStream_t stream) {
    const float* x_in = (const float*)d_in[0];
    const int* text_len = (const int*)d_in[1];
    const float* W_r = (const float*)d_in[2];
    const float* b_r = (const float*)d_in[3];
    const float* W_u = (const float*)d_in[4];
    const float* b_u = (const float*)d_in[5];
    const float* W_o = (const float*)d_in[6];
    const float* b_o = (const float*)d_in[7];

    float* xwork = (float*)d_out;
    float* seq_out = (float*)d_out + XELEMS;

    char* ws = (char*)d_ws;
    float* pe            = (float*)ws;                         // 204800 B
    __hip_bfloat16* WurT = (__hip_bfloat16*)(ws + 204800);     // [1024][1024] bf16 (u rows 0-511, r rows 512-1023)
    __hip_bfloat16* WoT  = (__hip_bfloat16*)(ws + 2301952);    // [512][1024] bf16
    __hip_bfloat16* cat  = (__hip_bfloat16*)(ws + 3350528);    // [51200][1536] bf16 (per-half; L3-resident)
    char* unionR         = ws + 160636928ull;                  // 67108864 B
    __hip_bfloat16* xTb  = (__hip_bfloat16*)unionR;            // [512][512][128] bf16
    __hip_bfloat16* upd  = (__hip_bfloat16*)unionR;            // [51200][512] bf16 (aliased; disjoint lifetime)

    pe_kernel<<<(L_ * D_ + 255) / 256, 256, 0, stream>>>(pe);
    cvtw_kernel<<<2048, 256, 0, stream>>>(W_u, WurT);
    cvtw_kernel<<<2048, 256, 0, stream>>>(W_r, WurT + 512 * 1024);
    cvtw_kernel<<<2048, 256, 0, stream>>>(W_o, WoT);

    // half-outer order: cat persists per-half across both layers; x-chain bf16 in cat.
    // Half-batch keeps cat (157MB) L3-resident — full-batch cat (315MB) thrashes L3 (R19).
    for (int h = 0; h < 2; ++h) {
        float* xdh = xwork + (size_t)h * HR * D_;
        // ---- layer 0: x from x_in f32 (phase 0 converts + transposes) ----
        attn_kernel<0><<<HB, 256, 0, stream>>>(x_in, pe, text_len, xTb, cat, h);
        gemm_gates<0, 0><<<3200, 256, 0, stream>>>(cat, WurT, b_u, b_r, upd, cat, nullptr);
        gemm_gates<1, 0><<<1600, 256, 0, stream>>>(cat, WoT, b_o, nullptr, upd, cat, nullptr);
        // ---- layer 1: x from cat bf16 (written in-place by layer-0 MODE1) ----
        attn_kernel<1><<<HB, 256, 0, stream>>>(nullptr, pe, text_len, xTb, cat, h);
        gemm_gates<0, 0><<<3200, 256, 0, stream>>>(cat, WurT, b_u, b_r, upd, cat, nullptr);
        gemm_gates<1, 1><<<1600, 256, 0, stream>>>(cat, WoT, b_o, nullptr, upd, cat, xdh);
    }
    pool_kernel<<<B_, 256, 0, stream>>>(xwork, text_len, seq_out);
}